// Round 5
// baseline (294.957 us; speedup 1.0000x reference)
//
#include <hip/hip_runtime.h>
#include <hip/hip_bf16.h>

#define T_SEQ 2048
#define D_IN  1024
#define DH    128

typedef __attribute__((ext_vector_type(8))) short bf16x8;   // 8 bf16 in 4 VGPRs
typedef __attribute__((ext_vector_type(4))) float f32x4;

__device__ inline short f2bf(float f) {
    union { float f; unsigned u; } a; a.f = f;
    unsigned u = a.u;
    return (short)((u + 0x7fffu + ((u >> 16) & 1u)) >> 16);   // RNE
}

#define GLL16(gsrc, ldst)                                                     \
    __builtin_amdgcn_global_load_lds(                                         \
        (const __attribute__((address_space(1))) void*)(gsrc),                \
        (__attribute__((address_space(3))) void*)(ldst), 16, 0, 0)

// ---- K0: prep. blocks [0,1536): W transpose -> WT[3][128][1024] bf16;
//          blocks [1536,9728): x f32 -> xb bf16 (8 elems/thread). ----------
__global__ __launch_bounds__(256) void k_prep(const float* __restrict__ x,
                                              const float* __restrict__ Wq,
                                              const float* __restrict__ Wk,
                                              const float* __restrict__ Wv,
                                              short* __restrict__ WT,
                                              short* __restrict__ xb) {
    int bid = blockIdx.x;
    int tid = threadIdx.x;
    if (bid < 1536) {
        int idx = bid * 256 + tid;
        int m = idx >> 17;
        int n = (idx >> 10) & (DH - 1);
        int k = idx & (D_IN - 1);
        const float* W = (m == 0) ? Wq : (m == 1) ? Wk : Wv;
        WT[idx] = f2bf(W[k * DH + n]);
    } else {
        int i = (bid - 1536) * 256 + tid;
        const float4* xs = (const float4*)x + (size_t)i * 2;
        float4 a = xs[0], b = xs[1];
        union { short s[8]; uint4 u; } c;
        c.s[0] = f2bf(a.x); c.s[1] = f2bf(a.y); c.s[2] = f2bf(a.z); c.s[3] = f2bf(a.w);
        c.s[4] = f2bf(b.x); c.s[5] = f2bf(b.y); c.s[6] = f2bf(b.z); c.s[7] = f2bf(b.w);
        ((uint4*)xb)[i] = c.u;
    }
}

// ---- K1: QKV GEMM, m97-style (unchanged from R4) -------------------------
__global__ __launch_bounds__(256) void k_qkv(const short* __restrict__ xb,
                                             const short* __restrict__ WT,
                                             const float* __restrict__ bq,
                                             const float* __restrict__ bk,
                                             const float* __restrict__ bv,
                                             short* __restrict__ Qb,
                                             short* __restrict__ Kb,
                                             short* __restrict__ VT) {
    __shared__ char As[2][8192];
    __shared__ char Bs[2][16384];
    int g = blockIdx.y;
    int m0 = blockIdx.x * 64;
    int tid = threadIdx.x;
    int wv = tid >> 6, lane = tid & 63;
    int lr = lane & 15, lg = lane >> 4;
    int wm = wv >> 1, wn = wv & 1;

    const char* Ab = (const char*)(xb + (size_t)m0 * D_IN);
    const char* Bb = (const char*)(WT + (size_t)g * DH * D_IN);
    int soff0 = wv * 1024 + lane * 16;

    const f32x4 z4 = {0.f, 0.f, 0.f, 0.f};
    f32x4 acc[2][4];
#pragma unroll
    for (int i = 0; i < 2; i++)
#pragma unroll
        for (int j = 0; j < 4; j++) acc[i][j] = z4;

#define STAGE(cur, kc)                                                        \
    do {                                                                      \
        _Pragma("unroll")                                                     \
        for (int i = 0; i < 2; i++) {                                         \
            int off = soff0 + i * 4096;                                       \
            int row = off >> 7, col = off & 127;                              \
            int cun = col ^ ((row & 7) << 4);                                 \
            GLL16(Ab + (size_t)row * 2048 + (kc) * 2 + cun,                   \
                  &As[cur][wv * 1024 + i * 4096]);                            \
        }                                                                     \
        _Pragma("unroll")                                                     \
        for (int i = 0; i < 4; i++) {                                         \
            int off = soff0 + i * 4096;                                       \
            int row = off >> 7, col = off & 127;                              \
            int cun = col ^ ((row & 7) << 4);                                 \
            GLL16(Bb + (size_t)row * 2048 + (kc) * 2 + cun,                   \
                  &Bs[cur][wv * 1024 + i * 4096]);                            \
        }                                                                     \
    } while (0)

    STAGE(0, 0);
    __syncthreads();

    int asw = (lr & 7) << 4;
    int cur = 0;
    for (int kc = 0; kc < D_IN; kc += 64) {
        if (kc + 64 < D_IN) STAGE(cur ^ 1, kc + 64);
#pragma unroll
        for (int ks2 = 0; ks2 < 2; ks2++) {
            int cb = (ks2 * 64 + lg * 16) ^ asw;
            bf16x8 af[2], bfr[4];
#pragma unroll
            for (int mt = 0; mt < 2; mt++)
                af[mt] = *(const bf16x8*)(&As[cur][(wm * 32 + mt * 16 + lr) * 128 + cb]);
#pragma unroll
            for (int nt = 0; nt < 4; nt++)
                bfr[nt] = *(const bf16x8*)(&Bs[cur][(wn * 64 + nt * 16 + lr) * 128 + cb]);
#pragma unroll
            for (int mt = 0; mt < 2; mt++)
#pragma unroll
                for (int nt = 0; nt < 4; nt++)
                    acc[mt][nt] = __builtin_amdgcn_mfma_f32_16x16x32_bf16(af[mt], bfr[nt], acc[mt][nt], 0, 0, 0);
        }
        __syncthreads();
        cur ^= 1;
    }

    const float* bias_p = (g == 0) ? bq : (g == 1) ? bk : bv;
#pragma unroll
    for (int nt = 0; nt < 4; nt++) {
        int n = wn * 64 + nt * 16 + lr;
        float bias = bias_p[n];
#pragma unroll
        for (int mt = 0; mt < 2; mt++)
#pragma unroll
            for (int r = 0; r < 4; r++) {
                int row = m0 + wm * 32 + mt * 16 + lg * 4 + r;
                short v16 = f2bf(acc[mt][nt][r] + bias);
                if (g == 0)      Qb[(size_t)row * DH + n] = v16;
                else if (g == 1) Kb[(size_t)row * DH + n] = v16;
                else {
                    int b = row >> 11, t = row & (T_SEQ - 1);
                    VT[((size_t)b * DH + n) * T_SEQ + t] = v16;
                }
            }
    }
#undef STAGE
}

// ---- K2: per-column partial Z, 2-deep pipelined Q-frag loads -------------
__global__ __launch_bounds__(256) void k_stats(const short* __restrict__ Qb,
                                               const short* __restrict__ Kb,
                                               float* __restrict__ Z_part) {
    int jb = blockIdx.x, qs = blockIdx.y, b = blockIdx.z;
    int tile0 = jb * 64;
    if (qs * 512 > tile0 + 63) return;
    int tid = threadIdx.x;
    int wv = tid >> 6, lane = tid & 63;
    int lr = lane & 15, lg = lane >> 4;
    int jsub = tile0 + wv * 16;

    const short* Kp = Kb + ((size_t)b * T_SEQ + jsub + lr) * DH;
    bf16x8 kf[4];
#pragma unroll
    for (int ks = 0; ks < 4; ks++) kf[ks] = *(const bf16x8*)(Kp + ks * 32 + lg * 8);

    float Z_run[4] = {0.f, 0.f, 0.f, 0.f};
    const short* Qbase = Qb + (size_t)b * T_SEQ * DH;
    const f32x4 z4 = {0.f, 0.f, 0.f, 0.f};
    int qt0 = (qs * 512) >> 4;
    int qtN = (min(qs * 512 + 512, tile0 + 64)) >> 4;

#define LOADQ(DST, QT)                                                        \
    do { _Pragma("unroll")                                                    \
        for (int ks = 0; ks < 4; ks++)                                        \
            DST[ks] = *(const bf16x8*)(Qbase + (size_t)((QT) * 16 + lr) * DH  \
                                       + ks * 32 + lg * 8);                   \
    } while (0)
#define QCOMP(QF, QT)                                                         \
    do { f32x4 s = z4;                                                        \
        _Pragma("unroll")                                                     \
        for (int ks = 0; ks < 4; ks++)                                        \
            s = __builtin_amdgcn_mfma_f32_16x16x32_bf16(kf[ks], QF[ks], s, 0, 0, 0); \
        int q = (QT) * 16 + lr;                                               \
        _Pragma("unroll")                                                     \
        for (int r = 0; r < 4; r++) {                                         \
            int j = jsub + lg * 4 + r;                                        \
            Z_run[r] += (q <= j) ? __expf(s[r]) : 0.f;                        \
        }                                                                     \
    } while (0)

    bf16x8 qfA[4], qfB[4];
    LOADQ(qfA, qt0);
    for (int qt = qt0; qt < qtN; qt += 2) {
        if (qt + 1 < qtN) LOADQ(qfB, qt + 1);
        QCOMP(qfA, qt);
        if (qt + 1 >= qtN) break;
        if (qt + 2 < qtN) LOADQ(qfA, qt + 2);
        QCOMP(qfB, qt + 1);
    }
#undef LOADQ
#undef QCOMP

#pragma unroll
    for (int r = 0; r < 4; r++) {
        float z = Z_run[r];
        for (int o = 1; o < 16; o <<= 1) z += __shfl_xor(z, o, 16);
        if (lr == 0)
            Z_part[((size_t)b * 4 + qs) * T_SEQ + jsub + lg * 4 + r] = z;
    }
}

// ---------------- K2b: merge partials -> 1/Z ----------------
__global__ __launch_bounds__(256) void k_sred(const float* __restrict__ Z_part,
                                              float* __restrict__ rZcol) {
    int idx = blockIdx.x * 256 + threadIdx.x;
    int b = idx >> 11, j = idx & (T_SEQ - 1);
    int ns = j / 512 + 1;
    float Z = 0.f;
    for (int qs = 0; qs < ns; qs++)
        Z += Z_part[((size_t)b * 4 + qs) * T_SEQ + j];
    rZcol[idx] = 1.0f / Z;
}

// ---- K3: barrier-free j-split. Block = 64 q x 512 j chunk; waves =
//      2 q-halves x 2 j-parities; per-wave K double-buffer; end LDS merge. -
__global__ __launch_bounds__(256, 2) void k_out(const short* __restrict__ Qb,
                                                const short* __restrict__ Kb,
                                                const short* __restrict__ VT,
                                                const float* __restrict__ rZcol,
                                                float* __restrict__ out) {
    __shared__ short pbuf[4][32 * 40];                 // per-wave P (32q x 32j)
    __shared__ float4 red[2][16 * 64];                 // j-parity merge, per q-half
    int qb = blockIdx.x, js = blockIdx.y, b = blockIdx.z;
    int jstart = max(js * 512, qb * 64);
    int jend = (js + 1) * 512;
    if (jstart >= jend) return;

    int tid = threadIdx.x;
    int wv = tid >> 6, lane = tid & 63;
    int lr = lane & 15, lg = lane >> 4;
    int qh = wv >> 1, jp = wv & 1;
    int qh0 = qb * 64 + qh * 32;

    const short* Qbase = Qb + (size_t)b * T_SEQ * DH;
    bf16x8 qf[2][4];
#pragma unroll
    for (int qt = 0; qt < 2; qt++)
#pragma unroll
        for (int ks = 0; ks < 4; ks++)
            qf[qt][ks] = *(const bf16x8*)(Qbase + (size_t)(qh0 + qt * 16 + lr) * DH + ks * 32 + lg * 8);

    const f32x4 z4 = {0.f, 0.f, 0.f, 0.f};
    f32x4 oacc[8][2];                                  // [vt][qt]
#pragma unroll
    for (int i = 0; i < 8; i++) { oacc[i][0] = z4; oacc[i][1] = z4; }

    const short* Kbase = Kb + (size_t)b * T_SEQ * DH;
    const short* VTb   = VT + (size_t)b * DH * T_SEQ;
    const float* zb = rZcol + (size_t)b * T_SEQ;
    short* pw = &pbuf[wv][0];

    int jstart_h = max(jstart, qh0);                   // skip fully-masked tiles
    int j0w = jstart_h + jp * 32;                      // this wave's first tile

    bf16x8 kfA[8], kfB[8], vf[8];

#define LOADK(DST, JT)                                                        \
    do { _Pragma("unroll")                                                    \
        for (int h = 0; h < 2; h++)                                           \
            _Pragma("unroll")                                                 \
            for (int ks = 0; ks < 4; ks++)                                    \
                DST[h * 4 + ks] = *(const bf16x8*)(Kbase +                    \
                    (size_t)((JT) + h * 16 + lr) * DH + ks * 32 + lg * 8);    \
    } while (0)

#define DOTILE(CUR, NXT, JT)                                                  \
    do {                                                                      \
        _Pragma("unroll")                                                     \
        for (int vt = 0; vt < 8; vt++)                                        \
            vf[vt] = *(const bf16x8*)(VTb + (size_t)(vt * 16 + lr) * T_SEQ    \
                                      + (JT) + lg * 8);                       \
        if ((JT) + 64 < jend) LOADK(NXT, (JT) + 64);                          \
        _Pragma("unroll")                                                     \
        for (int h = 0; h < 2; h++) {                                         \
            f32x4 s0 = z4, s1 = z4;                                           \
            _Pragma("unroll")                                                 \
            for (int ks = 0; ks < 4; ks++) {                                  \
                s0 = __builtin_amdgcn_mfma_f32_16x16x32_bf16(qf[0][ks], CUR[h * 4 + ks], s0, 0, 0, 0); \
                s1 = __builtin_amdgcn_mfma_f32_16x16x32_bf16(qf[1][ks], CUR[h * 4 + ks], s1, 0, 0, 0); \
            }                                                                 \
            int j = (JT) + h * 16 + lr;                                       \
            float rz = zb[j];                                                 \
            _Pragma("unroll")                                                 \
            for (int r = 0; r < 4; r++) {                                     \
                int q0_ = qh0 + lg * 4 + r;                                   \
                float p0 = (j >= q0_) ? __expf(s0[r]) * rz : 0.f;             \
                pw[(lg * 4 + r) * 40 + h * 16 + lr] = f2bf(p0);               \
                float p1 = (j >= q0_ + 16) ? __expf(s1[r]) * rz : 0.f;        \
                pw[(16 + lg * 4 + r) * 40 + h * 16 + lr] = f2bf(p1);          \
            }                                                                 \
        }                                                                     \
        {                                                                     \
            bf16x8 bp0 = *(const bf16x8*)&pw[lr * 40 + lg * 8];               \
            bf16x8 bp1 = *(const bf16x8*)&pw[(16 + lr) * 40 + lg * 8];        \
            _Pragma("unroll")                                                 \
            for (int vt = 0; vt < 8; vt++) {                                  \
                oacc[vt][0] = __builtin_amdgcn_mfma_f32_16x16x32_bf16(vf[vt], bp0, oacc[vt][0], 0, 0, 0); \
                oacc[vt][1] = __builtin_amdgcn_mfma_f32_16x16x32_bf16(vf[vt], bp1, oacc[vt][1], 0, 0, 0); \
            }                                                                 \
        }                                                                     \
    } while (0)

    if (j0w < jend) {
        LOADK(kfA, j0w);
        for (int jt = j0w; jt < jend; jt += 128) {
            DOTILE(kfA, kfB, jt);
            if (jt + 64 >= jend) break;
            DOTILE(kfB, kfA, jt + 64);
        }
    }
#undef LOADK
#undef DOTILE

    // merge j-parity partials: jp=1 writes, jp=0 adds + atomics to global
    __syncthreads();
    if (jp == 1) {
#pragma unroll
        for (int vt = 0; vt < 8; vt++)
#pragma unroll
            for (int qt = 0; qt < 2; qt++) {
                float4 t;
                t.x = oacc[vt][qt][0]; t.y = oacc[vt][qt][1];
                t.z = oacc[vt][qt][2]; t.w = oacc[vt][qt][3];
                red[qh][(vt * 2 + qt) * 64 + lane] = t;
            }
    }
    __syncthreads();
    if (jp == 0) {
#pragma unroll
        for (int vt = 0; vt < 8; vt++)
#pragma unroll
            for (int qt = 0; qt < 2; qt++) {
                float4 t = red[qh][(vt * 2 + qt) * 64 + lane];
                int q = qh0 + qt * 16 + lr;
                float* op = &out[((size_t)b * T_SEQ + q) * DH + vt * 16 + lg * 4];
                atomicAdd(op + 0, oacc[vt][qt][0] + t.x);
                atomicAdd(op + 1, oacc[vt][qt][1] + t.y);
                atomicAdd(op + 2, oacc[vt][qt][2] + t.z);
                atomicAdd(op + 3, oacc[vt][qt][3] + t.w);
            }
    }
}

extern "C" void kernel_launch(void* const* d_in, const int* in_sizes, int n_in,
                              void* d_out, int out_size, void* d_ws, size_t ws_size,
                              hipStream_t stream) {
    const float* x  = (const float*)d_in[0];
    const float* Wq = (const float*)d_in[1];
    const float* bq = (const float*)d_in[2];
    const float* Wk = (const float*)d_in[3];
    const float* bk = (const float*)d_in[4];
    const float* Wv = (const float*)d_in[5];
    const float* bv = (const float*)d_in[6];
    float* out = (float*)d_out;

    char* ws = (char*)d_ws;
    short* xb = (short*)ws;                                   // 32 MB
    short* WT = (short*)(ws + 33554432);                      // 768 KB
    short* Qb = (short*)(ws + 33554432 + 786432);             // 4 MB
    short* Kb = (short*)(ws + 33554432 + 786432 + 4194304);   // 4 MB
    short* VT = (short*)(ws + 33554432 + 786432 + 2 * 4194304);
    float* Z_part = (float*)(ws + 33554432 + 786432 + 3 * 4194304);  // 256 KB
    float* rZ     = (float*)(ws + 33554432 + 786432 + 3 * 4194304 + 262144);

    hipMemsetAsync(out, 0, (size_t)out_size * sizeof(float), stream);
    hipLaunchKernelGGL(k_prep, dim3(9728),     dim3(256), 0, stream, x, Wq, Wk, Wv, WT, xb);
    hipLaunchKernelGGL(k_qkv,  dim3(256, 3),   dim3(256), 0, stream, xb, WT, bq, bk, bv, Qb, Kb, VT);
    hipLaunchKernelGGL(k_stats,dim3(32, 4, 8), dim3(256), 0, stream, Qb, Kb, Z_part);
    hipLaunchKernelGGL(k_sred, dim3(64),       dim3(256), 0, stream, Z_part, rZ);
    hipLaunchKernelGGL(k_out,  dim3(32, 4, 8), dim3(256), 0, stream, Qb, Kb, VT, rZ, out);
}

// Round 7
// 234.628 us; speedup vs baseline: 1.2571x; 1.2571x over previous
//
#include <hip/hip_runtime.h>
#include <hip/hip_bf16.h>

#define T_SEQ 2048
#define D_IN  1024
#define DH    128

// packed lower-triangle P: per batch, q-tile qt (64 rows) stores cols j>=qt*64,
// row stride rs(qt)=2048-64*qt, tile base 2048*qt*(65-qt). total/batch:
#define P_ELEMS_PER_B 2162688
#define P_BYTES (8ull * P_ELEMS_PER_B * 2)      // 34,603,008

typedef __attribute__((ext_vector_type(8))) short bf16x8;   // 8 bf16 in 4 VGPRs
typedef __attribute__((ext_vector_type(4))) float f32x4;

__device__ inline short f2bf(float f) {
    union { float f; unsigned u; } a; a.f = f;
    unsigned u = a.u;
    return (short)((u + 0x7fffu + ((u >> 16) & 1u)) >> 16);   // RNE
}
__device__ inline float bf2f(short s) {
    union { unsigned u; float f; } a; a.u = ((unsigned)(unsigned short)s) << 16;
    return a.f;
}

#define GLL16(gsrc, ldst)                                                     \
    __builtin_amdgcn_global_load_lds(                                         \
        (const __attribute__((address_space(1))) void*)(gsrc),                \
        (__attribute__((address_space(3))) void*)(ldst), 16, 0, 0)

// ---- K0: prep. blocks [0,1536): W transpose -> WT[3][128][1024] bf16;
//          blocks [1536,9728): x f32 -> xb bf16 (8 elems/thread). ----------
__global__ __launch_bounds__(256) void k_prep(const float* __restrict__ x,
                                              const float* __restrict__ Wq,
                                              const float* __restrict__ Wk,
                                              const float* __restrict__ Wv,
                                              short* __restrict__ WT,
                                              short* __restrict__ xb) {
    int bid = blockIdx.x;
    int tid = threadIdx.x;
    if (bid < 1536) {
        int idx = bid * 256 + tid;
        int m = idx >> 17;
        int n = (idx >> 10) & (DH - 1);
        int k = idx & (D_IN - 1);
        const float* W = (m == 0) ? Wq : (m == 1) ? Wk : Wv;
        WT[idx] = f2bf(W[k * DH + n]);
    } else {
        int i = (bid - 1536) * 256 + tid;
        const float4* xs = (const float4*)x + (size_t)i * 2;
        float4 a = xs[0], b = xs[1];
        union { short s[8]; uint4 u; } c;
        c.s[0] = f2bf(a.x); c.s[1] = f2bf(a.y); c.s[2] = f2bf(a.z); c.s[3] = f2bf(a.w);
        c.s[4] = f2bf(b.x); c.s[5] = f2bf(b.y); c.s[6] = f2bf(b.z); c.s[7] = f2bf(b.w);
        ((uint4*)xb)[i] = c.u;
    }
}

// ---- K1: QKV GEMM, m97-style (unchanged — proven) ------------------------
__global__ __launch_bounds__(256) void k_qkv(const short* __restrict__ xb,
                                             const short* __restrict__ WT,
                                             const float* __restrict__ bq,
                                             const float* __restrict__ bk,
                                             const float* __restrict__ bv,
                                             short* __restrict__ Qb,
                                             short* __restrict__ Kb,
                                             short* __restrict__ VT) {
    __shared__ char As[2][8192];
    __shared__ char Bs[2][16384];
    int g = blockIdx.y;
    int m0 = blockIdx.x * 64;
    int tid = threadIdx.x;
    int wv = tid >> 6, lane = tid & 63;
    int lr = lane & 15, lg = lane >> 4;
    int wm = wv >> 1, wn = wv & 1;

    const char* Ab = (const char*)(xb + (size_t)m0 * D_IN);
    const char* Bb = (const char*)(WT + (size_t)g * DH * D_IN);
    int soff0 = wv * 1024 + lane * 16;

    const f32x4 z4 = {0.f, 0.f, 0.f, 0.f};
    f32x4 acc[2][4];
#pragma unroll
    for (int i = 0; i < 2; i++)
#pragma unroll
        for (int j = 0; j < 4; j++) acc[i][j] = z4;

#define STAGE(cur, kc)                                                        \
    do {                                                                      \
        _Pragma("unroll")                                                     \
        for (int i = 0; i < 2; i++) {                                         \
            int off = soff0 + i * 4096;                                       \
            int row = off >> 7, col = off & 127;                              \
            int cun = col ^ ((row & 7) << 4);                                 \
            GLL16(Ab + (size_t)row * 2048 + (kc) * 2 + cun,                   \
                  &As[cur][wv * 1024 + i * 4096]);                            \
        }                                                                     \
        _Pragma("unroll")                                                     \
        for (int i = 0; i < 4; i++) {                                         \
            int off = soff0 + i * 4096;                                       \
            int row = off >> 7, col = off & 127;                              \
            int cun = col ^ ((row & 7) << 4);                                 \
            GLL16(Bb + (size_t)row * 2048 + (kc) * 2 + cun,                   \
                  &Bs[cur][wv * 1024 + i * 4096]);                            \
        }                                                                     \
    } while (0)

    STAGE(0, 0);
    __syncthreads();

    int asw = (lr & 7) << 4;
    int cur = 0;
    for (int kc = 0; kc < D_IN; kc += 64) {
        if (kc + 64 < D_IN) STAGE(cur ^ 1, kc + 64);
#pragma unroll
        for (int ks2 = 0; ks2 < 2; ks2++) {
            int cb = (ks2 * 64 + lg * 16) ^ asw;
            bf16x8 af[2], bfr[4];
#pragma unroll
            for (int mt = 0; mt < 2; mt++)
                af[mt] = *(const bf16x8*)(&As[cur][(wm * 32 + mt * 16 + lr) * 128 + cb]);
#pragma unroll
            for (int nt = 0; nt < 4; nt++)
                bfr[nt] = *(const bf16x8*)(&Bs[cur][(wn * 64 + nt * 16 + lr) * 128 + cb]);
#pragma unroll
            for (int mt = 0; mt < 2; mt++)
#pragma unroll
                for (int nt = 0; nt < 4; nt++)
                    acc[mt][nt] = __builtin_amdgcn_mfma_f32_16x16x32_bf16(af[mt], bfr[nt], acc[mt][nt], 0, 0, 0);
        }
        __syncthreads();
        cur ^= 1;
    }

    const float* bias_p = (g == 0) ? bq : (g == 1) ? bk : bv;
#pragma unroll
    for (int nt = 0; nt < 4; nt++) {
        int n = wn * 64 + nt * 16 + lr;
        float bias = bias_p[n];
#pragma unroll
        for (int mt = 0; mt < 2; mt++)
#pragma unroll
            for (int r = 0; r < 4; r++) {
                int row = m0 + wm * 32 + mt * 16 + lg * 4 + r;
                short v16 = f2bf(acc[mt][nt][r] + bias);
                if (g == 0)      Qb[(size_t)row * DH + n] = v16;
                else if (g == 1) Kb[(size_t)row * DH + n] = v16;
                else {
                    int b = row >> 11, t = row & (T_SEQ - 1);
                    VT[((size_t)b * DH + n) * T_SEQ + t] = v16;
                }
            }
    }
#undef STAGE
}

// ---- K2: P = exp(Q K^T) lower-triangle tiles (packed) + column sums ------
// grid (jt 32, qt 32, b 8); block 64q x 64j; wave = 16 q rows.
__global__ __launch_bounds__(256) void k_score(const short* __restrict__ Qb,
                                               const short* __restrict__ Kb,
                                               short* __restrict__ P,
                                               float* __restrict__ Zc) {
    __shared__ short pbuf[4][16 * 72];
    int jt = blockIdx.x, qt = blockIdx.y, b = blockIdx.z;
    if (jt < qt) return;
    int tid = threadIdx.x;
    int wv = tid >> 6, lane = tid & 63;
    int lr = lane & 15, lg = lane >> 4;
    int qsub = qt * 64 + wv * 16;

    const short* Qp = Qb + ((size_t)b * T_SEQ + qsub + lr) * DH;
    bf16x8 qf[4];
#pragma unroll
    for (int ks = 0; ks < 4; ks++) qf[ks] = *(const bf16x8*)(Qp + ks * 32 + lg * 8);

    const short* Kbase = Kb + (size_t)b * T_SEQ * DH;
    float* Zb = Zc + (size_t)b * T_SEQ;
    short* pw = &pbuf[wv][0];
    const f32x4 z4 = {0.f, 0.f, 0.f, 0.f};

#pragma unroll
    for (int jsub = 0; jsub < 4; jsub++) {
        f32x4 s = z4;
#pragma unroll
        for (int ks = 0; ks < 4; ks++) {
            bf16x8 kfr = *(const bf16x8*)(Kbase +
                (size_t)(jt * 64 + jsub * 16 + lr) * DH + ks * 32 + lg * 8);
            s = __builtin_amdgcn_mfma_f32_16x16x32_bf16(qf[ks], kfr, s, 0, 0, 0);
        }
        int j = jt * 64 + jsub * 16 + lr;               // D row=q, col=j
        float csum = 0.f;
#pragma unroll
        for (int r = 0; r < 4; r++) {
            int q = qsub + lg * 4 + r;
            float p = (j >= q) ? __expf(s[r]) : 0.f;
            csum += p;
            pw[(lg * 4 + r) * 72 + jsub * 16 + lr] = f2bf(p);
        }
        csum += __shfl_xor(csum, 16);
        csum += __shfl_xor(csum, 32);
        if (lg == 0) atomicAdd(&Zb[j], csum);
    }
    // packed store: row q local = wv*16+lr, 2x 16B per lane
    int rs = 2048 - 64 * qt;
    short* Pb = P + (size_t)b * P_ELEMS_PER_B + (size_t)2048 * qt * (65 - qt);
    uint4 u0 = *(const uint4*)&pw[lr * 72 + lg * 8];
    uint4 u1 = *(const uint4*)&pw[lr * 72 + 32 + lg * 8];
    size_t rbase = (size_t)(wv * 16 + lr) * rs + (size_t)(jt - qt) * 64;
    *(uint4*)&Pb[rbase + lg * 8] = u0;
    *(uint4*)&Pb[rbase + 32 + lg * 8] = u1;
}

// ---- K3: VS[b][v][t] = VT[b][v][t] / Z[b][t] ----------------------------
__global__ __launch_bounds__(256) void k_vs(const short* __restrict__ VT,
                                            const float* __restrict__ Zc,
                                            short* __restrict__ VS) {
    int i = blockIdx.x * 256 + threadIdx.x;             // 262144 total
    int t8 = i & 255;
    int rest = i >> 8;                                  // b*128 + v
    int b = rest >> 7;
    size_t e = (size_t)rest * 2048 + t8 * 8;
    const float* Zp = Zc + (size_t)b * T_SEQ + t8 * 8;
    float4 z0 = *(const float4*)Zp;
    float4 z1 = *(const float4*)(Zp + 4);
    union { short s[8]; uint4 u; } in, ot;
    in.u = *(const uint4*)(VT + e);
    ot.s[0] = f2bf(bf2f(in.s[0]) / z0.x);
    ot.s[1] = f2bf(bf2f(in.s[1]) / z0.y);
    ot.s[2] = f2bf(bf2f(in.s[2]) / z0.z);
    ot.s[3] = f2bf(bf2f(in.s[3]) / z0.w);
    ot.s[4] = f2bf(bf2f(in.s[4]) / z1.x);
    ot.s[5] = f2bf(bf2f(in.s[5]) / z1.y);
    ot.s[6] = f2bf(bf2f(in.s[6]) / z1.z);
    ot.s[7] = f2bf(bf2f(in.s[7]) / z1.w);
    *(uint4*)(VS + e) = ot.u;
}

// ---- K4: out = P @ VS' (m97-style GEMM, triangle K-range, K-split x2) ----
// grid (qb 32, half 2, b 8). A = packed P rows (stride rs), B = VS rows (v).
// NOTE: A's column index is LOCAL (packed tile starts at j=qb*64); B's column
// index must be GLOBAL j = qb*64 + kc.  <-- R5 bug was the missing rebase.
__global__ __launch_bounds__(256) void k_pv(const short* __restrict__ P,
                                            const short* __restrict__ VS,
                                            float* __restrict__ out) {
    __shared__ char As[2][8192];
    __shared__ char Bs[2][16384];
    int qb = blockIdx.x, half = blockIdx.y, b = blockIdx.z;
    int jlo = max(qb * 64, half * 1024);
    int jhi = (half + 1) * 1024;
    if (jlo >= jhi) return;
    int kclo = jlo - qb * 64, kchi = jhi - qb * 64;     // local K range (elems)
    int rs2 = (2048 - 64 * qb) * 2;                     // A row stride bytes

    int tid = threadIdx.x;
    int wv = tid >> 6, lane = tid & 63;
    int lr = lane & 15, lg = lane >> 4;
    int wm = wv >> 1, wn = wv & 1;

    const char* Ab = (const char*)(P + (size_t)b * P_ELEMS_PER_B +
                                   (size_t)2048 * qb * (65 - qb));
    const char* Bb = (const char*)(VS + (size_t)b * DH * T_SEQ);
    int soff0 = wv * 1024 + lane * 16;

    const f32x4 z4 = {0.f, 0.f, 0.f, 0.f};
    f32x4 acc[2][4];
#pragma unroll
    for (int i = 0; i < 2; i++)
#pragma unroll
        for (int j = 0; j < 4; j++) acc[i][j] = z4;

#define STAGE(cur, kc)                                                        \
    do {                                                                      \
        _Pragma("unroll")                                                     \
        for (int i = 0; i < 2; i++) {                                         \
            int off = soff0 + i * 4096;                                       \
            int row = off >> 7, col = off & 127;                              \
            int cun = col ^ ((row & 7) << 4);                                 \
            GLL16(Ab + (size_t)row * rs2 + (kc) * 2 + cun,                    \
                  &As[cur][wv * 1024 + i * 4096]);                            \
        }                                                                     \
        _Pragma("unroll")                                                     \
        for (int i = 0; i < 4; i++) {                                         \
            int off = soff0 + i * 4096;                                       \
            int row = off >> 7, col = off & 127;                              \
            int cun = col ^ ((row & 7) << 4);                                 \
            GLL16(Bb + (size_t)row * 4096 + ((kc) + qb * 64) * 2 + cun,       \
                  &Bs[cur][wv * 1024 + i * 4096]);                            \
        }                                                                     \
    } while (0)

    STAGE(0, kclo);
    __syncthreads();

    int asw = (lr & 7) << 4;
    int cur = 0;
    for (int kc = kclo; kc < kchi; kc += 64) {
        if (kc + 64 < kchi) STAGE(cur ^ 1, kc + 64);
#pragma unroll
        for (int ks2 = 0; ks2 < 2; ks2++) {
            int cb = (ks2 * 64 + lg * 16) ^ asw;
            bf16x8 af[2], bfr[4];
#pragma unroll
            for (int mt = 0; mt < 2; mt++)
                af[mt] = *(const bf16x8*)(&As[cur][(wm * 32 + mt * 16 + lr) * 128 + cb]);
#pragma unroll
            for (int nt = 0; nt < 4; nt++)
                bfr[nt] = *(const bf16x8*)(&Bs[cur][(wn * 64 + nt * 16 + lr) * 128 + cb]);
#pragma unroll
            for (int mt = 0; mt < 2; mt++)
#pragma unroll
                for (int nt = 0; nt < 4; nt++)
                    acc[mt][nt] = __builtin_amdgcn_mfma_f32_16x16x32_bf16(af[mt], bfr[nt], acc[mt][nt], 0, 0, 0);
        }
        __syncthreads();
        cur ^= 1;
    }

#pragma unroll
    for (int nt = 0; nt < 4; nt++) {
        int n = wn * 64 + nt * 16 + lr;
#pragma unroll
        for (int mt = 0; mt < 2; mt++)
#pragma unroll
            for (int r = 0; r < 4; r++) {
                int row = qb * 64 + wm * 32 + mt * 16 + lg * 4 + r;
                atomicAdd(&out[((size_t)b * T_SEQ + row) * DH + n], acc[mt][nt][r]);
            }
    }
#undef STAGE
}

extern "C" void kernel_launch(void* const* d_in, const int* in_sizes, int n_in,
                              void* d_out, int out_size, void* d_ws, size_t ws_size,
                              hipStream_t stream) {
    const float* x  = (const float*)d_in[0];
    const float* Wq = (const float*)d_in[1];
    const float* bq = (const float*)d_in[2];
    const float* Wk = (const float*)d_in[3];
    const float* bk = (const float*)d_in[4];
    const float* Wv = (const float*)d_in[5];
    const float* bv = (const float*)d_in[6];
    float* out = (float*)d_out;

    char* ws = (char*)d_ws;
    short* P  = (short*)ws;                              // 34.6 MB (packed tri)
    short* xb = (short*)ws;                              // 32 MB, aliases P (dead after k_qkv)
    char*  p2 = ws + P_BYTES;
    short* WT = (short*)p2;                              // 768 KB
    short* Qb = (short*)(p2 + 786432);                   // 4 MB
    short* Kb = (short*)(p2 + 786432 + 4194304);         // 4 MB
    short* VT = (short*)(p2 + 786432 + 2 * 4194304);     // 4 MB
    short* VS = (short*)(p2 + 786432 + 3 * 4194304);     // 4 MB
    float* Zc = (float*)(p2 + 786432 + 4 * 4194304);     // 64 KB

    hipMemsetAsync(out, 0, (size_t)out_size * sizeof(float), stream);
    hipMemsetAsync(Zc, 0, 8 * T_SEQ * sizeof(float), stream);
    hipLaunchKernelGGL(k_prep,  dim3(9728),       dim3(256), 0, stream, x, Wq, Wk, Wv, WT, xb);
    hipLaunchKernelGGL(k_qkv,   dim3(256, 3),     dim3(256), 0, stream, xb, WT, bq, bk, bv, Qb, Kb, VT);
    hipLaunchKernelGGL(k_score, dim3(32, 32, 8),  dim3(256), 0, stream, Qb, Kb, P, Zc);
    hipLaunchKernelGGL(k_vs,    dim3(1024),       dim3(256), 0, stream, VT, Zc, VS);
    hipLaunchKernelGGL(k_pv,    dim3(32, 2, 8),   dim3(256), 0, stream, P, VS, out);
}

// Round 8
// 193.243 us; speedup vs baseline: 1.5264x; 1.2142x over previous
//
#include <hip/hip_runtime.h>
#include <hip/hip_bf16.h>

#define T_SEQ 2048
#define D_IN  1024
#define DH    128

// packed lower-triangle P: per batch, q-tile qt (64 rows) stores cols j>=qt*64,
// row stride rs(qt)=2048-64*qt, tile base 2048*qt*(65-qt). total/batch:
#define P_ELEMS_PER_B 2162688
#define P_BYTES (8ull * P_ELEMS_PER_B * 2)      // 34,603,008

typedef __attribute__((ext_vector_type(8))) short bf16x8;   // 8 bf16 in 4 VGPRs
typedef __attribute__((ext_vector_type(4))) float f32x4;

__device__ inline short f2bf(float f) {
    union { float f; unsigned u; } a; a.f = f;
    unsigned u = a.u;
    return (short)((u + 0x7fffu + ((u >> 16) & 1u)) >> 16);   // RNE
}
__device__ inline float bf2f(short s) {
    union { unsigned u; float f; } a; a.u = ((unsigned)(unsigned short)s) << 16;
    return a.f;
}

#define GLL16(gsrc, ldst)                                                     \
    __builtin_amdgcn_global_load_lds(                                         \
        (const __attribute__((address_space(1))) void*)(gsrc),                \
        (__attribute__((address_space(3))) void*)(ldst), 16, 0, 0)

// ---- K0: prep. blocks [0,1536): W transpose -> WT[3][128][1024] bf16;
//          blocks [1536,9728): x f32 -> xb bf16 (8 elems/thread). ----------
__global__ __launch_bounds__(256) void k_prep(const float* __restrict__ x,
                                              const float* __restrict__ Wq,
                                              const float* __restrict__ Wk,
                                              const float* __restrict__ Wv,
                                              short* __restrict__ WT,
                                              short* __restrict__ xb) {
    int bid = blockIdx.x;
    int tid = threadIdx.x;
    if (bid < 1536) {
        int idx = bid * 256 + tid;
        int m = idx >> 17;
        int n = (idx >> 10) & (DH - 1);
        int k = idx & (D_IN - 1);
        const float* W = (m == 0) ? Wq : (m == 1) ? Wk : Wv;
        WT[idx] = f2bf(W[k * DH + n]);
    } else {
        int i = (bid - 1536) * 256 + tid;
        const float4* xs = (const float4*)x + (size_t)i * 2;
        float4 a = xs[0], b = xs[1];
        union { short s[8]; uint4 u; } c;
        c.s[0] = f2bf(a.x); c.s[1] = f2bf(a.y); c.s[2] = f2bf(a.z); c.s[3] = f2bf(a.w);
        c.s[4] = f2bf(b.x); c.s[5] = f2bf(b.y); c.s[6] = f2bf(b.z); c.s[7] = f2bf(b.w);
        ((uint4*)xb)[i] = c.u;
    }
}

// ---- K1: QKV GEMM, m97-style (unchanged — proven) ------------------------
__global__ __launch_bounds__(256) void k_qkv(const short* __restrict__ xb,
                                             const short* __restrict__ WT,
                                             const float* __restrict__ bq,
                                             const float* __restrict__ bk,
                                             const float* __restrict__ bv,
                                             short* __restrict__ Qb,
                                             short* __restrict__ Kb,
                                             short* __restrict__ VT) {
    __shared__ char As[2][8192];
    __shared__ char Bs[2][16384];
    int g = blockIdx.y;
    int m0 = blockIdx.x * 64;
    int tid = threadIdx.x;
    int wv = tid >> 6, lane = tid & 63;
    int lr = lane & 15, lg = lane >> 4;
    int wm = wv >> 1, wn = wv & 1;

    const char* Ab = (const char*)(xb + (size_t)m0 * D_IN);
    const char* Bb = (const char*)(WT + (size_t)g * DH * D_IN);
    int soff0 = wv * 1024 + lane * 16;

    const f32x4 z4 = {0.f, 0.f, 0.f, 0.f};
    f32x4 acc[2][4];
#pragma unroll
    for (int i = 0; i < 2; i++)
#pragma unroll
        for (int j = 0; j < 4; j++) acc[i][j] = z4;

#define STAGE(cur, kc)                                                        \
    do {                                                                      \
        _Pragma("unroll")                                                     \
        for (int i = 0; i < 2; i++) {                                         \
            int off = soff0 + i * 4096;                                       \
            int row = off >> 7, col = off & 127;                              \
            int cun = col ^ ((row & 7) << 4);                                 \
            GLL16(Ab + (size_t)row * 2048 + (kc) * 2 + cun,                   \
                  &As[cur][wv * 1024 + i * 4096]);                            \
        }                                                                     \
        _Pragma("unroll")                                                     \
        for (int i = 0; i < 4; i++) {                                         \
            int off = soff0 + i * 4096;                                       \
            int row = off >> 7, col = off & 127;                              \
            int cun = col ^ ((row & 7) << 4);                                 \
            GLL16(Bb + (size_t)row * 2048 + (kc) * 2 + cun,                   \
                  &Bs[cur][wv * 1024 + i * 4096]);                            \
        }                                                                     \
    } while (0)

    STAGE(0, 0);
    __syncthreads();

    int asw = (lr & 7) << 4;
    int cur = 0;
    for (int kc = 0; kc < D_IN; kc += 64) {
        if (kc + 64 < D_IN) STAGE(cur ^ 1, kc + 64);
#pragma unroll
        for (int ks2 = 0; ks2 < 2; ks2++) {
            int cb = (ks2 * 64 + lg * 16) ^ asw;
            bf16x8 af[2], bfr[4];
#pragma unroll
            for (int mt = 0; mt < 2; mt++)
                af[mt] = *(const bf16x8*)(&As[cur][(wm * 32 + mt * 16 + lr) * 128 + cb]);
#pragma unroll
            for (int nt = 0; nt < 4; nt++)
                bfr[nt] = *(const bf16x8*)(&Bs[cur][(wn * 64 + nt * 16 + lr) * 128 + cb]);
#pragma unroll
            for (int mt = 0; mt < 2; mt++)
#pragma unroll
                for (int nt = 0; nt < 4; nt++)
                    acc[mt][nt] = __builtin_amdgcn_mfma_f32_16x16x32_bf16(af[mt], bfr[nt], acc[mt][nt], 0, 0, 0);
        }
        __syncthreads();
        cur ^= 1;
    }

    const float* bias_p = (g == 0) ? bq : (g == 1) ? bk : bv;
#pragma unroll
    for (int nt = 0; nt < 4; nt++) {
        int n = wn * 64 + nt * 16 + lr;
        float bias = bias_p[n];
#pragma unroll
        for (int mt = 0; mt < 2; mt++)
#pragma unroll
            for (int r = 0; r < 4; r++) {
                int row = m0 + wm * 32 + mt * 16 + lg * 4 + r;
                short v16 = f2bf(acc[mt][nt][r] + bias);
                if (g == 0)      Qb[(size_t)row * DH + n] = v16;
                else if (g == 1) Kb[(size_t)row * DH + n] = v16;
                else {
                    int b = row >> 11, t = row & (T_SEQ - 1);
                    VT[((size_t)b * DH + n) * T_SEQ + t] = v16;
                }
            }
    }
#undef STAGE
}

// ---- K2: P = exp(Q K^T) packed triangle, k_qkv-style pipelined strips ----
// grid (qt 32, jc 4, b 8); block = 64 q x 512 j (8 j-tiles), double-buffered
// K staging via global_load_lds + XOR swizzle; Q in regs amortized.
__global__ __launch_bounds__(256) void k_score(const short* __restrict__ Qb,
                                               const short* __restrict__ Kb,
                                               short* __restrict__ P,
                                               float* __restrict__ Zc) {
    __shared__ char Ks[2][16384];                 // 64 rows x 256B
    __shared__ short pbuf[4][16 * 72];
    int qt = blockIdx.x, jc = blockIdx.y, b = blockIdx.z;
    if (qt > jc * 8 + 7) return;                  // strip entirely left of diag
    int jt0 = max(jc * 8, qt), jtend = jc * 8 + 8;

    int tid = threadIdx.x;
    int wv = tid >> 6, lane = tid & 63;
    int lr = lane & 15, lg = lane >> 4;
    int qsub = qt * 64 + wv * 16;

    const short* Qp = Qb + ((size_t)b * T_SEQ + qsub + lr) * DH;
    bf16x8 qf[4];
#pragma unroll
    for (int ks = 0; ks < 4; ks++) qf[ks] = *(const bf16x8*)(Qp + ks * 32 + lg * 8);

    const char* Kbase = (const char*)(Kb + (size_t)b * T_SEQ * DH);
    float* Zb = Zc + (size_t)b * T_SEQ;
    short* pw = &pbuf[wv][0];
    int rs = 2048 - 64 * qt;
    short* Pb = P + (size_t)b * P_ELEMS_PER_B + (size_t)2048 * qt * (65 - qt);
    const f32x4 z4 = {0.f, 0.f, 0.f, 0.f};

    // stage: issue i covers rows i*16 + wv*4 + lg (lane*16 -> +lg row, +lr*16B col)
#define KSTAGE(cur, jt)                                                       \
    do { _Pragma("unroll")                                                    \
        for (int i = 0; i < 4; i++) {                                         \
            int row = i * 16 + wv * 4 + lg;                                   \
            int col = (lr * 16) ^ ((row & 7) << 4);                           \
            GLL16(Kbase + (size_t)((jt) * 64 + row) * 256 + col,              \
                  &Ks[cur][i * 4096 + wv * 1024]);                            \
        } } while (0)

    KSTAGE(0, jt0);
    __syncthreads();
    int cur = 0;
    int asw = (lr & 7) << 4;
    for (int jt = jt0; jt < jtend; jt++) {
        if (jt + 1 < jtend) KSTAGE(cur ^ 1, jt + 1);
#pragma unroll
        for (int jsub = 0; jsub < 4; jsub++) {
            f32x4 s = z4;
#pragma unroll
            for (int ks = 0; ks < 4; ks++) {
                bf16x8 kfr = *(const bf16x8*)&Ks[cur][(jsub * 16 + lr) * 256 +
                                                      ((ks * 64 + lg * 16) ^ asw)];
                s = __builtin_amdgcn_mfma_f32_16x16x32_bf16(qf[ks], kfr, s, 0, 0, 0);
            }
            int j = jt * 64 + jsub * 16 + lr;           // D row=q, col=j
            float csum = 0.f;
#pragma unroll
            for (int r = 0; r < 4; r++) {
                int q = qsub + lg * 4 + r;
                float p = (j >= q) ? __expf(s[r]) : 0.f;
                csum += p;
                pw[(lg * 4 + r) * 72 + jsub * 16 + lr] = f2bf(p);
            }
            csum += __shfl_xor(csum, 16);
            csum += __shfl_xor(csum, 32);
            if (lg == 0) atomicAdd(&Zb[j], csum);
        }
        // packed store of this tile (row q local = wv*16+lr)
        uint4 u0 = *(const uint4*)&pw[lr * 72 + lg * 8];
        uint4 u1 = *(const uint4*)&pw[lr * 72 + 32 + lg * 8];
        size_t rbase = (size_t)(wv * 16 + lr) * rs + (size_t)(jt - qt) * 64;
        *(uint4*)&Pb[rbase + lg * 8] = u0;
        *(uint4*)&Pb[rbase + 32 + lg * 8] = u1;
        __syncthreads();
        cur ^= 1;
    }
#undef KSTAGE
}

// ---- K3: VS[b][v][t] = VT[b][v][t] / Z[b][t] ----------------------------
__global__ __launch_bounds__(256) void k_vs(const short* __restrict__ VT,
                                            const float* __restrict__ Zc,
                                            short* __restrict__ VS) {
    int i = blockIdx.x * 256 + threadIdx.x;             // 262144 total
    int t8 = i & 255;
    int rest = i >> 8;                                  // b*128 + v
    int b = rest >> 7;
    size_t e = (size_t)rest * 2048 + t8 * 8;
    const float* Zp = Zc + (size_t)b * T_SEQ + t8 * 8;
    float4 z0 = *(const float4*)Zp;
    float4 z1 = *(const float4*)(Zp + 4);
    union { short s[8]; uint4 u; } in, ot;
    in.u = *(const uint4*)(VT + e);
    ot.s[0] = f2bf(bf2f(in.s[0]) / z0.x);
    ot.s[1] = f2bf(bf2f(in.s[1]) / z0.y);
    ot.s[2] = f2bf(bf2f(in.s[2]) / z0.z);
    ot.s[3] = f2bf(bf2f(in.s[3]) / z0.w);
    ot.s[4] = f2bf(bf2f(in.s[4]) / z1.x);
    ot.s[5] = f2bf(bf2f(in.s[5]) / z1.y);
    ot.s[6] = f2bf(bf2f(in.s[6]) / z1.z);
    ot.s[7] = f2bf(bf2f(in.s[7]) / z1.w);
    *(uint4*)(VS + e) = ot.u;
}

// ---- K4: out = P @ VS' (m97-style GEMM, triangle K-range, K-split x2) ----
// grid (qb 32, half 2, b 8). A = packed P rows (stride rs), B = VS rows (v).
// A's column index is LOCAL (packed tile starts at j=qb*64); B's is GLOBAL.
__global__ __launch_bounds__(256) void k_pv(const short* __restrict__ P,
                                            const short* __restrict__ VS,
                                            float* __restrict__ out) {
    __shared__ char As[2][8192];
    __shared__ char Bs[2][16384];
    int qb = blockIdx.x, half = blockIdx.y, b = blockIdx.z;
    int jlo = max(qb * 64, half * 1024);
    int jhi = (half + 1) * 1024;
    if (jlo >= jhi) return;
    int kclo = jlo - qb * 64, kchi = jhi - qb * 64;     // local K range (elems)
    int rs2 = (2048 - 64 * qb) * 2;                     // A row stride bytes

    int tid = threadIdx.x;
    int wv = tid >> 6, lane = tid & 63;
    int lr = lane & 15, lg = lane >> 4;
    int wm = wv >> 1, wn = wv & 1;

    const char* Ab = (const char*)(P + (size_t)b * P_ELEMS_PER_B +
                                   (size_t)2048 * qb * (65 - qb));
    const char* Bb = (const char*)(VS + (size_t)b * DH * T_SEQ);
    int soff0 = wv * 1024 + lane * 16;

    const f32x4 z4 = {0.f, 0.f, 0.f, 0.f};
    f32x4 acc[2][4];
#pragma unroll
    for (int i = 0; i < 2; i++)
#pragma unroll
        for (int j = 0; j < 4; j++) acc[i][j] = z4;

#define STAGE(cur, kc)                                                        \
    do {                                                                      \
        _Pragma("unroll")                                                     \
        for (int i = 0; i < 2; i++) {                                         \
            int off = soff0 + i * 4096;                                       \
            int row = off >> 7, col = off & 127;                              \
            int cun = col ^ ((row & 7) << 4);                                 \
            GLL16(Ab + (size_t)row * rs2 + (kc) * 2 + cun,                    \
                  &As[cur][wv * 1024 + i * 4096]);                            \
        }                                                                     \
        _Pragma("unroll")                                                     \
        for (int i = 0; i < 4; i++) {                                         \
            int off = soff0 + i * 4096;                                       \
            int row = off >> 7, col = off & 127;                              \
            int cun = col ^ ((row & 7) << 4);                                 \
            GLL16(Bb + (size_t)row * 4096 + ((kc) + qb * 64) * 2 + cun,       \
                  &Bs[cur][wv * 1024 + i * 4096]);                            \
        }                                                                     \
    } while (0)

    STAGE(0, kclo);
    __syncthreads();

    int asw = (lr & 7) << 4;
    int cur = 0;
    for (int kc = kclo; kc < kchi; kc += 64) {
        if (kc + 64 < kchi) STAGE(cur ^ 1, kc + 64);
#pragma unroll
        for (int ks2 = 0; ks2 < 2; ks2++) {
            int cb = (ks2 * 64 + lg * 16) ^ asw;
            bf16x8 af[2], bfr[4];
#pragma unroll
            for (int mt = 0; mt < 2; mt++)
                af[mt] = *(const bf16x8*)(&As[cur][(wm * 32 + mt * 16 + lr) * 128 + cb]);
#pragma unroll
            for (int nt = 0; nt < 4; nt++)
                bfr[nt] = *(const bf16x8*)(&Bs[cur][(wn * 64 + nt * 16 + lr) * 128 + cb]);
#pragma unroll
            for (int mt = 0; mt < 2; mt++)
#pragma unroll
                for (int nt = 0; nt < 4; nt++)
                    acc[mt][nt] = __builtin_amdgcn_mfma_f32_16x16x32_bf16(af[mt], bfr[nt], acc[mt][nt], 0, 0, 0);
        }
        __syncthreads();
        cur ^= 1;
    }

#pragma unroll
    for (int nt = 0; nt < 4; nt++) {
        int n = wn * 64 + nt * 16 + lr;
#pragma unroll
        for (int mt = 0; mt < 2; mt++)
#pragma unroll
            for (int r = 0; r < 4; r++) {
                int row = qb * 64 + wm * 32 + mt * 16 + lg * 4 + r;
                atomicAdd(&out[((size_t)b * T_SEQ + row) * DH + n], acc[mt][nt][r]);
            }
    }
#undef STAGE
}

extern "C" void kernel_launch(void* const* d_in, const int* in_sizes, int n_in,
                              void* d_out, int out_size, void* d_ws, size_t ws_size,
                              hipStream_t stream) {
    const float* x  = (const float*)d_in[0];
    const float* Wq = (const float*)d_in[1];
    const float* bq = (const float*)d_in[2];
    const float* Wk = (const float*)d_in[3];
    const float* bk = (const float*)d_in[4];
    const float* Wv = (const float*)d_in[5];
    const float* bv = (const float*)d_in[6];
    float* out = (float*)d_out;

    char* ws = (char*)d_ws;
    short* P  = (short*)ws;                              // 34.6 MB (packed tri)
    short* xb = (short*)ws;                              // 32 MB, aliases P (dead after k_qkv)
    char*  p2 = ws + P_BYTES;
    short* WT = (short*)p2;                              // 768 KB
    short* Qb = (short*)(p2 + 786432);                   // 4 MB
    short* Kb = (short*)(p2 + 786432 + 4194304);         // 4 MB
    short* VT = (short*)(p2 + 786432 + 2 * 4194304);     // 4 MB
    short* VS = (short*)(p2 + 786432 + 3 * 4194304);     // 4 MB
    float* Zc = (float*)(p2 + 786432 + 4 * 4194304);     // 64 KB

    hipMemsetAsync(out, 0, (size_t)out_size * sizeof(float), stream);
    hipMemsetAsync(Zc, 0, 8 * T_SEQ * sizeof(float), stream);
    hipLaunchKernelGGL(k_prep,  dim3(9728),       dim3(256), 0, stream, x, Wq, Wk, Wv, WT, xb);
    hipLaunchKernelGGL(k_qkv,   dim3(256, 3),     dim3(256), 0, stream, xb, WT, bq, bk, bv, Qb, Kb, VT);
    hipLaunchKernelGGL(k_score, dim3(32, 4, 8),   dim3(256), 0, stream, Qb, Kb, P, Zc);
    hipLaunchKernelGGL(k_vs,    dim3(1024),       dim3(256), 0, stream, VT, Zc, VS);
    hipLaunchKernelGGL(k_pv,    dim3(32, 2, 8),   dim3(256), 0, stream, P, VS, out);
}

// Round 9
// 189.603 us; speedup vs baseline: 1.5557x; 1.0192x over previous
//
#include <hip/hip_runtime.h>
#include <hip/hip_bf16.h>

#define T_SEQ 2048
#define D_IN  1024
#define DH    128

// packed lower-triangle P: per batch, 64-q-tile T stores cols j>=64T,
// row stride rs(T)=2048-64T, tile base 2048*T*(65-T). total/batch:
#define P_ELEMS_PER_B 2162688
#define P_BYTES (8ull * P_ELEMS_PER_B * 2)      // 34,603,008

typedef __attribute__((ext_vector_type(8))) short bf16x8;   // 8 bf16 in 4 VGPRs
typedef __attribute__((ext_vector_type(4))) float f32x4;

__device__ inline short f2bf(float f) {
    union { float f; unsigned u; } a; a.f = f;
    unsigned u = a.u;
    return (short)((u + 0x7fffu + ((u >> 16) & 1u)) >> 16);   // RNE
}
__device__ inline float bf2f(short s) {
    union { unsigned u; float f; } a; a.u = ((unsigned)(unsigned short)s) << 16;
    return a.f;
}

#define GLL16(gsrc, ldst)                                                     \
    __builtin_amdgcn_global_load_lds(                                         \
        (const __attribute__((address_space(1))) void*)(gsrc),                \
        (__attribute__((address_space(3))) void*)(ldst), 16, 0, 0)

// ---- K0: prep. blocks [0,1536): W transpose -> WT[3][128][1024] bf16;
//          blocks [1536,9728): x f32 -> xb bf16 (8 elems/thread). ----------
__global__ __launch_bounds__(256) void k_prep(const float* __restrict__ x,
                                              const float* __restrict__ Wq,
                                              const float* __restrict__ Wk,
                                              const float* __restrict__ Wv,
                                              short* __restrict__ WT,
                                              short* __restrict__ xb) {
    int bid = blockIdx.x;
    int tid = threadIdx.x;
    if (bid < 1536) {
        int idx = bid * 256 + tid;
        int m = idx >> 17;
        int n = (idx >> 10) & (DH - 1);
        int k = idx & (D_IN - 1);
        const float* W = (m == 0) ? Wq : (m == 1) ? Wk : Wv;
        WT[idx] = f2bf(W[k * DH + n]);
    } else {
        int i = (bid - 1536) * 256 + tid;
        const float4* xs = (const float4*)x + (size_t)i * 2;
        float4 a = xs[0], b = xs[1];
        union { short s[8]; uint4 u; } c;
        c.s[0] = f2bf(a.x); c.s[1] = f2bf(a.y); c.s[2] = f2bf(a.z); c.s[3] = f2bf(a.w);
        c.s[4] = f2bf(b.x); c.s[5] = f2bf(b.y); c.s[6] = f2bf(b.z); c.s[7] = f2bf(b.w);
        ((uint4*)xb)[i] = c.u;
    }
}

// ---- K1: QKV GEMM, m97-style (unchanged — proven) ------------------------
__global__ __launch_bounds__(256) void k_qkv(const short* __restrict__ xb,
                                             const short* __restrict__ WT,
                                             const float* __restrict__ bq,
                                             const float* __restrict__ bk,
                                             const float* __restrict__ bv,
                                             short* __restrict__ Qb,
                                             short* __restrict__ Kb,
                                             short* __restrict__ VT) {
    __shared__ char As[2][8192];
    __shared__ char Bs[2][16384];
    int g = blockIdx.y;
    int m0 = blockIdx.x * 64;
    int tid = threadIdx.x;
    int wv = tid >> 6, lane = tid & 63;
    int lr = lane & 15, lg = lane >> 4;
    int wm = wv >> 1, wn = wv & 1;

    const char* Ab = (const char*)(xb + (size_t)m0 * D_IN);
    const char* Bb = (const char*)(WT + (size_t)g * DH * D_IN);
    int soff0 = wv * 1024 + lane * 16;

    const f32x4 z4 = {0.f, 0.f, 0.f, 0.f};
    f32x4 acc[2][4];
#pragma unroll
    for (int i = 0; i < 2; i++)
#pragma unroll
        for (int j = 0; j < 4; j++) acc[i][j] = z4;

#define STAGE(cur, kc)                                                        \
    do {                                                                      \
        _Pragma("unroll")                                                     \
        for (int i = 0; i < 2; i++) {                                         \
            int off = soff0 + i * 4096;                                       \
            int row = off >> 7, col = off & 127;                              \
            int cun = col ^ ((row & 7) << 4);                                 \
            GLL16(Ab + (size_t)row * 2048 + (kc) * 2 + cun,                   \
                  &As[cur][wv * 1024 + i * 4096]);                            \
        }                                                                     \
        _Pragma("unroll")                                                     \
        for (int i = 0; i < 4; i++) {                                         \
            int off = soff0 + i * 4096;                                       \
            int row = off >> 7, col = off & 127;                              \
            int cun = col ^ ((row & 7) << 4);                                 \
            GLL16(Bb + (size_t)row * 2048 + (kc) * 2 + cun,                   \
                  &Bs[cur][wv * 1024 + i * 4096]);                            \
        }                                                                     \
    } while (0)

    STAGE(0, 0);
    __syncthreads();

    int asw = (lr & 7) << 4;
    int cur = 0;
    for (int kc = 0; kc < D_IN; kc += 64) {
        if (kc + 64 < D_IN) STAGE(cur ^ 1, kc + 64);
#pragma unroll
        for (int ks2 = 0; ks2 < 2; ks2++) {
            int cb = (ks2 * 64 + lg * 16) ^ asw;
            bf16x8 af[2], bfr[4];
#pragma unroll
            for (int mt = 0; mt < 2; mt++)
                af[mt] = *(const bf16x8*)(&As[cur][(wm * 32 + mt * 16 + lr) * 128 + cb]);
#pragma unroll
            for (int nt = 0; nt < 4; nt++)
                bfr[nt] = *(const bf16x8*)(&Bs[cur][(wn * 64 + nt * 16 + lr) * 128 + cb]);
#pragma unroll
            for (int mt = 0; mt < 2; mt++)
#pragma unroll
                for (int nt = 0; nt < 4; nt++)
                    acc[mt][nt] = __builtin_amdgcn_mfma_f32_16x16x32_bf16(af[mt], bfr[nt], acc[mt][nt], 0, 0, 0);
        }
        __syncthreads();
        cur ^= 1;
    }

    const float* bias_p = (g == 0) ? bq : (g == 1) ? bk : bv;
#pragma unroll
    for (int nt = 0; nt < 4; nt++) {
        int n = wn * 64 + nt * 16 + lr;
        float bias = bias_p[n];
#pragma unroll
        for (int mt = 0; mt < 2; mt++)
#pragma unroll
            for (int r = 0; r < 4; r++) {
                int row = m0 + wm * 32 + mt * 16 + lg * 4 + r;
                short v16 = f2bf(acc[mt][nt][r] + bias);
                if (g == 0)      Qb[(size_t)row * DH + n] = v16;
                else if (g == 1) Kb[(size_t)row * DH + n] = v16;
                else {
                    int b = row >> 11, t = row & (T_SEQ - 1);
                    VT[((size_t)b * DH + n) * T_SEQ + t] = v16;
                }
            }
    }
#undef STAGE
}

// ---- K2: P = exp(Q K^T) packed triangle. Block = 128 q x 512 j strip;
// two 64-q subtiles (A,B) share the double-buffered K staging. ------------
__global__ __launch_bounds__(256) void k_score(const short* __restrict__ Qb,
                                               const short* __restrict__ Kb,
                                               short* __restrict__ P,
                                               float* __restrict__ Zc) {
    __shared__ char Ks[2][16384];                 // 64 j rows x 256B
    __shared__ short pbuf[4][16 * 72];            // per-wave, reused for A then B
    int qt = blockIdx.x, jc = blockIdx.y, b = blockIdx.z;
    int t64A = qt * 2, t64B = qt * 2 + 1;
    if (t64A > jc * 8 + 7) return;                // strip entirely left of diag
    int jt0 = max(jc * 8, t64A), jtend = jc * 8 + 8;

    int tid = threadIdx.x;
    int wv = tid >> 6, lane = tid & 63;
    int lr = lane & 15, lg = lane >> 4;
    int qsubA = qt * 128 + wv * 16;
    int qsubB = qsubA + 64;

    const short* Qbase = Qb + (size_t)b * T_SEQ * DH;
    bf16x8 qfA[4], qfB[4];
#pragma unroll
    for (int ks = 0; ks < 4; ks++) {
        qfA[ks] = *(const bf16x8*)(Qbase + (size_t)(qsubA + lr) * DH + ks * 32 + lg * 8);
        qfB[ks] = *(const bf16x8*)(Qbase + (size_t)(qsubB + lr) * DH + ks * 32 + lg * 8);
    }

    const char* Kbase = (const char*)(Kb + (size_t)b * T_SEQ * DH);
    float* Zb = Zc + (size_t)b * T_SEQ;
    short* pw = &pbuf[wv][0];
    int rsA = 2048 - 64 * t64A, rsB = 2048 - 64 * t64B;
    short* PbA = P + (size_t)b * P_ELEMS_PER_B + (size_t)2048 * t64A * (65 - t64A);
    short* PbB = P + (size_t)b * P_ELEMS_PER_B + (size_t)2048 * t64B * (65 - t64B);
    const f32x4 z4 = {0.f, 0.f, 0.f, 0.f};

#define KSTAGE(cur, jt)                                                       \
    do { _Pragma("unroll")                                                    \
        for (int i = 0; i < 4; i++) {                                         \
            int row = i * 16 + wv * 4 + lg;                                   \
            int col = (lr * 16) ^ ((row & 7) << 4);                           \
            GLL16(Kbase + (size_t)((jt) * 64 + row) * 256 + col,              \
                  &Ks[cur][i * 4096 + wv * 1024]);                            \
        } } while (0)

    KSTAGE(0, jt0);
    __syncthreads();
    int cur = 0;
    int asw = (lr & 7) << 4;
    for (int jt = jt0; jt < jtend; jt++) {
        if (jt + 1 < jtend) KSTAGE(cur ^ 1, jt + 1);
        // ---- pass A (q rows qsubA..+15) ----
#pragma unroll
        for (int jsub = 0; jsub < 4; jsub++) {
            f32x4 s = z4;
#pragma unroll
            for (int ks = 0; ks < 4; ks++) {
                bf16x8 kfr = *(const bf16x8*)&Ks[cur][(jsub * 16 + lr) * 256 +
                                                      ((ks * 64 + lg * 16) ^ asw)];
                s = __builtin_amdgcn_mfma_f32_16x16x32_bf16(qfA[ks], kfr, s, 0, 0, 0);
            }
            int j = jt * 64 + jsub * 16 + lr;
            float csum = 0.f;
#pragma unroll
            for (int r = 0; r < 4; r++) {
                int q = qsubA + lg * 4 + r;
                float p = (j >= q) ? __expf(s[r]) : 0.f;
                csum += p;
                pw[(lg * 4 + r) * 72 + jsub * 16 + lr] = f2bf(p);
            }
            csum += __shfl_xor(csum, 16);
            csum += __shfl_xor(csum, 32);
            if (lg == 0) atomicAdd(&Zb[j], csum);
        }
        {
            uint4 u0 = *(const uint4*)&pw[lr * 72 + lg * 8];
            uint4 u1 = *(const uint4*)&pw[lr * 72 + 32 + lg * 8];
            size_t rbase = (size_t)(wv * 16 + lr) * rsA + (size_t)(jt - t64A) * 64;
            *(uint4*)&PbA[rbase + lg * 8] = u0;
            *(uint4*)&PbA[rbase + 32 + lg * 8] = u1;
        }
        // ---- pass B (q rows qsubB..+15); fully masked when jt < t64B ----
        if (jt >= t64B) {
#pragma unroll
            for (int jsub = 0; jsub < 4; jsub++) {
                f32x4 s = z4;
#pragma unroll
                for (int ks = 0; ks < 4; ks++) {
                    bf16x8 kfr = *(const bf16x8*)&Ks[cur][(jsub * 16 + lr) * 256 +
                                                          ((ks * 64 + lg * 16) ^ asw)];
                    s = __builtin_amdgcn_mfma_f32_16x16x32_bf16(qfB[ks], kfr, s, 0, 0, 0);
                }
                int j = jt * 64 + jsub * 16 + lr;
                float csum = 0.f;
#pragma unroll
                for (int r = 0; r < 4; r++) {
                    int q = qsubB + lg * 4 + r;
                    float p = (j >= q) ? __expf(s[r]) : 0.f;
                    csum += p;
                    pw[(lg * 4 + r) * 72 + jsub * 16 + lr] = f2bf(p);
                }
                csum += __shfl_xor(csum, 16);
                csum += __shfl_xor(csum, 32);
                if (lg == 0) atomicAdd(&Zb[j], csum);
            }
            uint4 u0 = *(const uint4*)&pw[lr * 72 + lg * 8];
            uint4 u1 = *(const uint4*)&pw[lr * 72 + 32 + lg * 8];
            size_t rbase = (size_t)(wv * 16 + lr) * rsB + (size_t)(jt - t64B) * 64;
            *(uint4*)&PbB[rbase + lg * 8] = u0;
            *(uint4*)&PbB[rbase + 32 + lg * 8] = u1;
        }
        __syncthreads();
        cur ^= 1;
    }
#undef KSTAGE
}

// ---- K3: VS[b][v][t] = VT[b][v][t] / Z[b][t] ----------------------------
__global__ __launch_bounds__(256) void k_vs(const short* __restrict__ VT,
                                            const float* __restrict__ Zc,
                                            short* __restrict__ VS) {
    int i = blockIdx.x * 256 + threadIdx.x;             // 262144 total
    int t8 = i & 255;
    int rest = i >> 8;                                  // b*128 + v
    int b = rest >> 7;
    size_t e = (size_t)rest * 2048 + t8 * 8;
    const float* Zp = Zc + (size_t)b * T_SEQ + t8 * 8;
    float4 z0 = *(const float4*)Zp;
    float4 z1 = *(const float4*)(Zp + 4);
    union { short s[8]; uint4 u; } in, ot;
    in.u = *(const uint4*)(VT + e);
    ot.s[0] = f2bf(bf2f(in.s[0]) / z0.x);
    ot.s[1] = f2bf(bf2f(in.s[1]) / z0.y);
    ot.s[2] = f2bf(bf2f(in.s[2]) / z0.z);
    ot.s[3] = f2bf(bf2f(in.s[3]) / z0.w);
    ot.s[4] = f2bf(bf2f(in.s[4]) / z1.x);
    ot.s[5] = f2bf(bf2f(in.s[5]) / z1.y);
    ot.s[6] = f2bf(bf2f(in.s[6]) / z1.z);
    ot.s[7] = f2bf(bf2f(in.s[7]) / z1.w);
    *(uint4*)(VS + e) = ot.u;
}

// ---- K4: partial = P @ VS (m97-style, triangle K-range, K-split x2) ------
// grid (qb 32, half 2, b 8). Plain stores into O0 (half=0) / O1 (half=1);
// each (row,n) written by exactly one block per half -> no atomics.
__global__ __launch_bounds__(256) void k_pv(const short* __restrict__ P,
                                            const short* __restrict__ VS,
                                            float* __restrict__ O0,
                                            float* __restrict__ O1) {
    __shared__ char As[2][8192];
    __shared__ char Bs[2][16384];
    int qb = blockIdx.x, half = blockIdx.y, b = blockIdx.z;
    int jlo = max(qb * 64, half * 1024);
    int jhi = (half + 1) * 1024;
    if (jlo >= jhi) return;
    int kclo = jlo - qb * 64, kchi = jhi - qb * 64;     // local K range (elems)
    int rs2 = (2048 - 64 * qb) * 2;                     // A row stride bytes

    int tid = threadIdx.x;
    int wv = tid >> 6, lane = tid & 63;
    int lr = lane & 15, lg = lane >> 4;
    int wm = wv >> 1, wn = wv & 1;

    const char* Ab = (const char*)(P + (size_t)b * P_ELEMS_PER_B +
                                   (size_t)2048 * qb * (65 - qb));
    const char* Bb = (const char*)(VS + (size_t)b * DH * T_SEQ);
    int soff0 = wv * 1024 + lane * 16;

    const f32x4 z4 = {0.f, 0.f, 0.f, 0.f};
    f32x4 acc[2][4];
#pragma unroll
    for (int i = 0; i < 2; i++)
#pragma unroll
        for (int j = 0; j < 4; j++) acc[i][j] = z4;

#define STAGE(cur, kc)                                                        \
    do {                                                                      \
        _Pragma("unroll")                                                     \
        for (int i = 0; i < 2; i++) {                                         \
            int off = soff0 + i * 4096;                                       \
            int row = off >> 7, col = off & 127;                              \
            int cun = col ^ ((row & 7) << 4);                                 \
            GLL16(Ab + (size_t)row * rs2 + (kc) * 2 + cun,                    \
                  &As[cur][wv * 1024 + i * 4096]);                            \
        }                                                                     \
        _Pragma("unroll")                                                     \
        for (int i = 0; i < 4; i++) {                                         \
            int off = soff0 + i * 4096;                                       \
            int row = off >> 7, col = off & 127;                              \
            int cun = col ^ ((row & 7) << 4);                                 \
            GLL16(Bb + (size_t)row * 4096 + ((kc) + qb * 64) * 2 + cun,       \
                  &Bs[cur][wv * 1024 + i * 4096]);                            \
        }                                                                     \
    } while (0)

    STAGE(0, kclo);
    __syncthreads();

    int asw = (lr & 7) << 4;
    int cur = 0;
    for (int kc = kclo; kc < kchi; kc += 64) {
        if (kc + 64 < kchi) STAGE(cur ^ 1, kc + 64);
#pragma unroll
        for (int ks2 = 0; ks2 < 2; ks2++) {
            int cb = (ks2 * 64 + lg * 16) ^ asw;
            bf16x8 af[2], bfr[4];
#pragma unroll
            for (int mt = 0; mt < 2; mt++)
                af[mt] = *(const bf16x8*)(&As[cur][(wm * 32 + mt * 16 + lr) * 128 + cb]);
#pragma unroll
            for (int nt = 0; nt < 4; nt++)
                bfr[nt] = *(const bf16x8*)(&Bs[cur][(wn * 64 + nt * 16 + lr) * 128 + cb]);
#pragma unroll
            for (int mt = 0; mt < 2; mt++)
#pragma unroll
                for (int nt = 0; nt < 4; nt++)
                    acc[mt][nt] = __builtin_amdgcn_mfma_f32_16x16x32_bf16(af[mt], bfr[nt], acc[mt][nt], 0, 0, 0);
        }
        __syncthreads();
        cur ^= 1;
    }

    float* Ob = half ? O1 : O0;
#pragma unroll
    for (int nt = 0; nt < 4; nt++) {
        int n = wn * 64 + nt * 16 + lr;
#pragma unroll
        for (int mt = 0; mt < 2; mt++)
#pragma unroll
            for (int r = 0; r < 4; r++) {
                int row = qb * 64 + wm * 32 + mt * 16 + lg * 4 + r;
                Ob[((size_t)b * T_SEQ + row) * DH + n] = acc[mt][nt][r];
            }
    }
#undef STAGE
}

// ---- K5: out = O1 + (q<1024 ? O0 : 0), float4 ---------------------------
__global__ __launch_bounds__(256) void k_mrg(const float* __restrict__ O0,
                                             const float* __restrict__ O1,
                                             float* __restrict__ out) {
    int i4 = blockIdx.x * 256 + threadIdx.x;            // 0..524287
    float4 a = ((const float4*)O1)[i4];
    if ((i4 & 32768) == 0) {                            // q < 1024 (bit 15 within batch)
        float4 b = ((const float4*)O0)[i4];
        a.x += b.x; a.y += b.y; a.z += b.z; a.w += b.w;
    }
    ((float4*)out)[i4] = a;
}

extern "C" void kernel_launch(void* const* d_in, const int* in_sizes, int n_in,
                              void* d_out, int out_size, void* d_ws, size_t ws_size,
                              hipStream_t stream) {
    const float* x  = (const float*)d_in[0];
    const float* Wq = (const float*)d_in[1];
    const float* bq = (const float*)d_in[2];
    const float* Wk = (const float*)d_in[3];
    const float* bk = (const float*)d_in[4];
    const float* Wv = (const float*)d_in[5];
    const float* bv = (const float*)d_in[6];
    float* out = (float*)d_out;

    char* ws = (char*)d_ws;
    short* P  = (short*)ws;                              // 34.6 MB (packed tri)
    short* xb = (short*)ws;                              // 32 MB, aliases P (dead after k_qkv)
    char*  p2 = ws + P_BYTES;
    short* WT = (short*)p2;                              // 768 KB
    short* Qb = (short*)(p2 + 786432);                   // 4 MB
    short* Kb = (short*)(p2 + 786432 + 4194304);         // 4 MB
    short* VT = (short*)(p2 + 786432 + 2 * 4194304);     // 4 MB
    short* VS = (short*)(p2 + 786432 + 3 * 4194304);     // 4 MB
    float* Zc = (float*)(p2 + 786432 + 4 * 4194304);     // 64 KB
    float* O0 = (float*)(p2 + 786432 + 4 * 4194304 + 65536);   // 8 MB
    float* O1 = O0 + 2097152;                                  // 8 MB

    hipMemsetAsync(Zc, 0, 8 * T_SEQ * sizeof(float), stream);
    hipLaunchKernelGGL(k_prep,  dim3(9728),       dim3(256), 0, stream, x, Wq, Wk, Wv, WT, xb);
    hipLaunchKernelGGL(k_qkv,   dim3(256, 3),     dim3(256), 0, stream, xb, WT, bq, bk, bv, Qb, Kb, VT);
    hipLaunchKernelGGL(k_score, dim3(16, 4, 8),   dim3(256), 0, stream, Qb, Kb, P, Zc);
    hipLaunchKernelGGL(k_vs,    dim3(1024),       dim3(256), 0, stream, VT, Zc, VS);
    hipLaunchKernelGGL(k_pv,    dim3(32, 2, 8),   dim3(256), 0, stream, P, VS, O0, O1);
    hipLaunchKernelGGL(k_mrg,   dim3(2048),       dim3(256), 0, stream, O0, O1, out);
}